// Round 7
// baseline (366.382 us; speedup 1.0000x reference)
//
#include <hip/hip_runtime.h>
#include <hip/hip_bf16.h>

#define TSTEPS 60
#define HIDDEN 64

typedef __attribute__((ext_vector_type(8))) short bf16x8;
typedef __attribute__((ext_vector_type(4))) float f32x4;

// Setup-only (loop-invariant) scalar conversion (compiler RNE emulation, cold path).
__device__ __forceinline__ short f2bf(float f) {
    return __builtin_bit_cast(short, __float2bfloat16(f));
}

// Hot-path pack: two f32 -> one u32 of 2 bf16, round-to-nearest (ties away).
// Pure bit ops, no asm (round-5 lesson: v_cvt_pk_bf16_f32 asm gave wrong halves
// -> recurrence exploded; keep the proven bit-op version).
__device__ __forceinline__ unsigned pack2_bf16(float a, float b) {
    unsigned ua = __builtin_bit_cast(unsigned, a) + 0x8000u;
    unsigned ub = __builtin_bit_cast(unsigned, b) + 0x8000u;
    return (ua >> 16) | (ub & 0xFFFF0000u);
}

// One wave = 16 samples, sequential over TSTEPS.
//   L1: D1 = W1^T(64x4,K-pad32) @ x(4x16)      -> h1 (64x16)
//   L2: D2 = W2^T(64x64)        @ h1(64x16)    -> h2 (64x16)
//   L3: delta = relu(h2) . W3  (4-chain VALU dot + shfl_xor reduce over g-groups)
// D-frag: col=lane&15 (sample), row=(lane>>4)*4+reg.  A/B-frags: 8 contig k per lane.
//
// Fences: h1 round-trips through LDS with uint2-typed writes and bf16x8-typed
// reads of the same bytes (TBAA says non-aliasing). The zero-instruction
// compiler fences pin write->read (RAW) and read->next-write (WAR) order.
__global__ __launch_bounds__(256)
void ffn_mfma(const float* __restrict__ feat,
              const float* __restrict__ W1, const float* __restrict__ b1,
              const float* __restrict__ W2, const float* __restrict__ b2,
              const float* __restrict__ W3, const float* __restrict__ b3,
              float* __restrict__ out, int N) {
    __shared__ short h1s[4][1024];  // per-wave 16x64 bf16, XOR-swizzled

    const int lane = threadIdx.x & 63;
    const int wave = threadIdx.x >> 6;
    const int c = lane & 15;     // sample column
    const int g = lane >> 4;     // k/row group
    const int nbase = blockIdx.x * 64 + wave * 16;
    if (nbase >= N) return;

    // ---- loop-invariant weight fragments ----
    // W1^T as A: A[row=c][k=8g+j] = W1[k][m*16+c], zero for k>=4.
    bf16x8 a1[4];
#pragma unroll
    for (int m = 0; m < 4; ++m) {
        bf16x8 v = {0, 0, 0, 0, 0, 0, 0, 0};
        if (g == 0) {
#pragma unroll
            for (int j = 0; j < 4; ++j) v[j] = f2bf(W1[j * 64 + m * 16 + c]);
        }
        a1[m] = v;
    }
    // W2^T as A: A[row=c][k=32q+8g+j] = W2[k][m*16+c].
    bf16x8 a2[4][2];
#pragma unroll
    for (int m = 0; m < 4; ++m)
#pragma unroll
        for (int q = 0; q < 2; ++q) {
            bf16x8 v;
#pragma unroll
            for (int j = 0; j < 8; ++j)
                v[j] = f2bf(W2[(32 * q + 8 * g + j) * 64 + m * 16 + c]);
            a2[m][q] = v;
        }
    // Per-lane bias / W3 fragments in D layout (row = m*16+4g+r).
    f32x4 b1f[4], b2f[4], w3f[4];
#pragma unroll
    for (int m = 0; m < 4; ++m)
#pragma unroll
        for (int r = 0; r < 4; ++r) {
            b1f[m][r] = b1[m * 16 + 4 * g + r];
            b2f[m][r] = b2[m * 16 + 4 * g + r];
            w3f[m][r] = W3[m * 16 + 4 * g + r];
        }
    const float b3v = b3[0];

    // LDS addressing: logical byte (c*128 + hid*2), XOR-swizzled by ((c&7)<<4).
    char* hbase = (char*)&h1s[wave][0];
    const int swz = (c & 7) << 4;
    int woff[4], roff[2];
#pragma unroll
    for (int m = 0; m < 4; ++m) woff[m] = (c * 128 + m * 32 + g * 8) ^ swz;
#pragma unroll
    for (int q = 0; q < 2; ++q) roff[q] = (c * 128 + q * 64 + g * 16) ^ swz;

    const float* fp = feat + (size_t)(nbase + c) * (TSTEPS * 3);
    const f32x4* fq = (const f32x4*)fp;   // 48B per 4-step block, 16B-aligned
    float* o = out + (size_t)(nbase + c) * TSTEPS;

    // One recurrence step: consumes (f0,f1,f2,din), returns new delta.
    auto step = [&](float f0, float f1, float f2, float din) -> float {
        // x-frag (B of L1): rows 0..3 = [f0,f1,f2,din]; rows>=4 don't care (A is 0).
        uint4 xu;
        xu.x = pack2_bf16(f0, f1);
        xu.y = pack2_bf16(f2, din);
        xu.z = 0u; xu.w = 0u;
        const bf16x8 xb = __builtin_bit_cast(bf16x8, xu);

        // L1: h1 = relu(W1^T @ x + b1)
        f32x4 h1a[4];
#pragma unroll
        for (int m = 0; m < 4; ++m)
            h1a[m] = __builtin_amdgcn_mfma_f32_16x16x32_bf16(a1[m], xb, b1f[m], 0, 0, 0);

        // relu + pack + LDS write ([c][m*16+4g..+3], 8B each)
#pragma unroll
        for (int m = 0; m < 4; ++m) {
            uint2 u;
            u.x = pack2_bf16(fmaxf(h1a[m][0], 0.f), fmaxf(h1a[m][1], 0.f));
            u.y = pack2_bf16(fmaxf(h1a[m][2], 0.f), fmaxf(h1a[m][3], 0.f));
            *(uint2*)(hbase + woff[m]) = u;
        }
        __asm__ volatile("" ::: "memory");  // RAW fence: reads stay below writes

        // B-frags of L2: lane reads h1[ k=32q+8g..+7 ][c] = 16B contiguous
        const bf16x8 hb0 = *(const bf16x8*)(hbase + roff[0]);
        const bf16x8 hb1 = *(const bf16x8*)(hbase + roff[1]);
        __asm__ volatile("" ::: "memory");  // WAR fence: next step's writes stay below reads

        // L2: h2 = W2^T @ h1 + b2
        f32x4 acc[4];
#pragma unroll
        for (int m = 0; m < 4; ++m) {
            acc[m] = __builtin_amdgcn_mfma_f32_16x16x32_bf16(a2[m][0], hb0, b2f[m], 0, 0, 0);
            acc[m] = __builtin_amdgcn_mfma_f32_16x16x32_bf16(a2[m][1], hb1, acc[m], 0, 0, 0);
        }

        // L3: delta = relu(h2) . W3 + b3 -- 4 independent chains, tree sum.
        float pr0 = 0.f, pr1 = 0.f, pr2 = 0.f, pr3 = 0.f;
#pragma unroll
        for (int m = 0; m < 4; ++m) {
            pr0 = fmaf(fmaxf(acc[m][0], 0.f), w3f[m][0], pr0);
            pr1 = fmaf(fmaxf(acc[m][1], 0.f), w3f[m][1], pr1);
            pr2 = fmaf(fmaxf(acc[m][2], 0.f), w3f[m][2], pr2);
            pr3 = fmaf(fmaxf(acc[m][3], 0.f), w3f[m][3], pr3);
        }
        float p = (pr0 + pr1) + (pr2 + pr3);
        p += __shfl_xor(p, 16, 64);
        p += __shfl_xor(p, 32, 64);
        return p + b3v;
    };

    // Feature double-buffer: cf* hold the current 4-step block (12 floats),
    // nf* prefetch the next block while the current one is computed.
    f32x4 cf0 = fq[0], cf1 = fq[1], cf2 = fq[2];
    float delta = 0.0f;

    for (int tb = 0; tb < TSTEPS; tb += 4) {
        f32x4 nf0, nf1, nf2;
        if (tb + 4 < TSTEPS) {
            const int bq = 3 * ((tb >> 2) + 1);
            nf0 = fq[bq + 0]; nf1 = fq[bq + 1]; nf2 = fq[bq + 2];
        }

        const float d0 = step(cf0[0], cf0[1], cf0[2], delta);
        const float d1 = step(cf0[3], cf1[0], cf1[1], d0);
        const float d2 = step(cf1[2], cf1[3], cf2[0], d1);
        const float d3 = step(cf2[1], cf2[2], cf2[3], d2);
        delta = d3;

        if (g == 0) {
            f32x4 v = {d0, d1, d2, d3};
            *(f32x4*)(o + tb) = v;   // 16B-aligned (240 % 16 == 0)
        }
        cf0 = nf0; cf1 = nf1; cf2 = nf2;
    }
}

extern "C" void kernel_launch(void* const* d_in, const int* in_sizes, int n_in,
                              void* d_out, int out_size, void* d_ws, size_t ws_size,
                              hipStream_t stream) {
    const float* feat = (const float*)d_in[0];
    const float* W1   = (const float*)d_in[1];
    const float* b1   = (const float*)d_in[2];
    const float* W2   = (const float*)d_in[3];
    const float* b2   = (const float*)d_in[4];
    const float* W3   = (const float*)d_in[5];
    const float* b3   = (const float*)d_in[6];
    float* out = (float*)d_out;

    const int N = in_sizes[0] / (TSTEPS * 3);
    const int block = 256;                 // 4 waves x 16 samples = 64 samples/block
    const int grid = (N + 63) / 64;
    ffn_mfma<<<grid, block, 0, stream>>>(feat, W1, b1, W2, b2, W3, b3, out, N);
}

// Round 8
// 304.805 us; speedup vs baseline: 1.2020x; 1.2020x over previous
//
#include <hip/hip_runtime.h>
#include <hip/hip_bf16.h>

#define TSTEPS 60

typedef __attribute__((ext_vector_type(8))) short bf16x8;
typedef __attribute__((ext_vector_type(16))) float f32x16;

// Setup-only scalar conversion.
__device__ __forceinline__ short f2bf(float f) {
    return __builtin_bit_cast(short, __float2bfloat16(f));
}
// Hot-path pack: two f32 -> u32 of 2 bf16 (round-to-nearest, ties away).
// Proven in R6; do NOT replace with v_cvt_pk asm (R5 blowup).
__device__ __forceinline__ unsigned pack2_bf16(float a, float b) {
    unsigned ua = __builtin_bit_cast(unsigned, a) + 0x8000u;
    unsigned ub = __builtin_bit_cast(unsigned, b) + 0x8000u;
    return (ua >> 16) | (ub & 0xFFFF0000u);
}

// One wave = 32 samples via 32x32x16 MFMA.
//   L1: h1(64x32) = relu( [W1^T | b1](64x5 in K=16) @ [x;1](5x32) )   -- 2 MFMA
//   L2: h2(64x32) = [W2^T | b2](64x65 in K=80) @ [h1;1](65x32)        -- 10 MFMA
//   L3: delta = relu(h2).W3 + b3  (VALU dot, one shfl_xor(32) reduce)
// Frags: A row=lane&31, k=8*(lane>>5)+j ; D col=lane&31, row=(reg&3)+8*(reg>>2)+4*(lane>>5).
// Fences: h1 LDS round-trip is uint2-write / bf16x8-read (TBAA non-aliasing) ->
// zero-instruction compiler fences pin RAW and WAR order (R4/R5 lesson).
__global__ __launch_bounds__(256)
void ffn_mfma32(const float* __restrict__ feat,
                const float* __restrict__ W1, const float* __restrict__ b1,
                const float* __restrict__ W2, const float* __restrict__ b2,
                const float* __restrict__ W3, const float* __restrict__ b3,
                float* __restrict__ out, int N) {
    __shared__ short h1s[4][2048];    // per-wave 32x64 bf16, XOR-swizzled (4KB each)
    __shared__ float dlt[4][32 * 61]; // per-wave output staging, stride 61 = conflict-free

    const int lane = threadIdx.x & 63;
    const int wave = threadIdx.x >> 6;
    const int col  = lane & 31;   // sample column
    const int half = lane >> 5;   // k-group half
    const int nbase = blockIdx.x * 128 + wave * 32;
    if (nbase >= N) return;

    const unsigned hmask = half ? 0u : 0xFFFFFFFFu;

    // ---- loop-invariant fragments ----
    // L1 A: rows m*32+col; k<4 -> W1[k][row], k==4 -> b1[row] (bias row), else 0.
    bf16x8 a1[2];
#pragma unroll
    for (int m = 0; m < 2; ++m) {
        bf16x8 v = {0,0,0,0,0,0,0,0};
        if (half == 0) {
            const int row = m*32 + col;
#pragma unroll
            for (int j = 0; j < 4; ++j) v[j] = f2bf(W1[j*64 + row]);
            v[4] = f2bf(b1[row]);
        }
        a1[m] = v;
    }
    // L2 A: kt 0..3 = W2^T, kt 4 = bias column (k=64 -> b2[row]).
    bf16x8 a2[2][5];
#pragma unroll
    for (int m = 0; m < 2; ++m) {
        const int row = m*32 + col;
#pragma unroll
        for (int kt = 0; kt < 4; ++kt) {
            bf16x8 v;
#pragma unroll
            for (int j = 0; j < 8; ++j)
                v[j] = f2bf(W2[(16*kt + 8*half + j)*64 + row]);
            a2[m][kt] = v;
        }
        bf16x8 v = {0,0,0,0,0,0,0,0};
        if (half == 0) v[0] = f2bf(b2[row]);
        a2[m][4] = v;
    }
    // W3 in D layout (f32, full precision dot).
    float w3f[2][16];
#pragma unroll
    for (int m = 0; m < 2; ++m)
#pragma unroll
        for (int r = 0; r < 16; ++r)
            w3f[m][r] = W3[m*32 + (r&3) + 8*(r>>2) + 4*half];
    const float b3v = b3[0];

    // Constant ones B-frag for L2's bias K-tile (h1-extended row k=64 == 1.0).
    uint4 onesu; onesu.x = 0x3F80u & hmask; onesu.y = 0u; onesu.z = 0u; onesu.w = 0u;
    const bf16x8 hb4 = __builtin_bit_cast(bf16x8, onesu);

    f32x16 zc;
#pragma unroll
    for (int r = 0; r < 16; ++r) zc[r] = 0.0f;

    // LDS addressing: logical byte (col*128 + k*2), XOR-swizzled by ((col&7)<<4).
    char* hbase = (char*)h1s[wave];
    const int swz = (col & 7) << 4;
    int woff[2][4];
#pragma unroll
    for (int m = 0; m < 2; ++m)
#pragma unroll
        for (int q = 0; q < 4; ++q)
            woff[m][q] = (col*128 + m*64 + q*16 + half*8) ^ swz;   // rows 32m+8q+4h..+3
    int roff[4];
#pragma unroll
    for (int kt = 0; kt < 4; ++kt)
        roff[kt] = (col*128 + kt*32 + half*16) ^ swz;              // k = 16kt+8h..+7

    const float* fp = feat + (size_t)(nbase + col) * (TSTEPS * 3);
    float* dl = dlt[wave];
    float f0 = fp[0], f1 = fp[1], f2v = fp[2];
    float delta = 0.0f;

#pragma unroll 2
    for (int t = 0; t < TSTEPS; ++t) {
        const int tn = (t + 1 < TSTEPS) ? t + 1 : t;   // clamped prefetch (no OOB)
        const float nf0 = fp[tn*3+0], nf1 = fp[tn*3+1], nf2 = fp[tn*3+2];

        // x-frag: k rows [f0,f1,f2,delta,1,0...]; half==1 lanes all zero.
        uint4 xu;
        xu.x = pack2_bf16(f0, f1) & hmask;
        xu.y = pack2_bf16(f2v, delta) & hmask;
        xu.z = 0x3F80u & hmask;
        xu.w = 0u;
        const bf16x8 xb = __builtin_bit_cast(bf16x8, xu);

        // L1 (bias folded): h1 = relu(W1ext @ xext)
        f32x16 h1a[2];
        h1a[0] = __builtin_amdgcn_mfma_f32_32x32x16_bf16(a1[0], xb, zc, 0, 0, 0);
        h1a[1] = __builtin_amdgcn_mfma_f32_32x32x16_bf16(a1[1], xb, zc, 0, 0, 0);

        // relu + pack + LDS write: uint2 covers rows 32m+8q+4h..+3 of col.
#pragma unroll
        for (int m = 0; m < 2; ++m)
#pragma unroll
            for (int q = 0; q < 4; ++q) {
                uint2 u;
                u.x = pack2_bf16(fmaxf(h1a[m][4*q+0], 0.f), fmaxf(h1a[m][4*q+1], 0.f));
                u.y = pack2_bf16(fmaxf(h1a[m][4*q+2], 0.f), fmaxf(h1a[m][4*q+3], 0.f));
                *(uint2*)(hbase + woff[m][q]) = u;
            }
        __asm__ volatile("" ::: "memory");  // RAW fence

        const bf16x8 hb0 = *(const bf16x8*)(hbase + roff[0]);
        const bf16x8 hb1 = *(const bf16x8*)(hbase + roff[1]);
        const bf16x8 hb2 = *(const bf16x8*)(hbase + roff[2]);
        const bf16x8 hb3 = *(const bf16x8*)(hbase + roff[3]);
        __asm__ volatile("" ::: "memory");  // WAR fence

        // L2 (bias folded via ones K-tile)
        f32x16 acc[2];
#pragma unroll
        for (int m = 0; m < 2; ++m) {
            f32x16 a = __builtin_amdgcn_mfma_f32_32x32x16_bf16(a2[m][0], hb0, zc, 0, 0, 0);
            a = __builtin_amdgcn_mfma_f32_32x32x16_bf16(a2[m][1], hb1, a, 0, 0, 0);
            a = __builtin_amdgcn_mfma_f32_32x32x16_bf16(a2[m][2], hb2, a, 0, 0, 0);
            a = __builtin_amdgcn_mfma_f32_32x32x16_bf16(a2[m][3], hb3, a, 0, 0, 0);
            a = __builtin_amdgcn_mfma_f32_32x32x16_bf16(a2[m][4], hb4, a, 0, 0, 0);
            acc[m] = a;
        }

        // L3 dot: 4 independent chains; one shfl_xor(32) completes the 64-row sum.
        float p0 = 0.f, p1 = 0.f, p2 = 0.f, p3 = 0.f;
#pragma unroll
        for (int m = 0; m < 2; ++m)
#pragma unroll
            for (int q = 0; q < 4; ++q) {
                p0 = fmaf(fmaxf(acc[m][4*q+0], 0.f), w3f[m][4*q+0], p0);
                p1 = fmaf(fmaxf(acc[m][4*q+1], 0.f), w3f[m][4*q+1], p1);
                p2 = fmaf(fmaxf(acc[m][4*q+2], 0.f), w3f[m][4*q+2], p2);
                p3 = fmaf(fmaxf(acc[m][4*q+3], 0.f), w3f[m][4*q+3], p3);
            }
        float p = (p0 + p1) + (p2 + p3);
        p += __shfl_xor(p, 32, 64);
        delta = p + b3v;

        if (half == 0) dl[col*61 + t] = delta;
        f0 = nf0; f1 = nf1; f2v = nf2;
    }

    // Coalesced flush: out[nbase*60 + i], i = col*60 + t ; LDS idx = col*61+t = i + i/60.
    float* ob = out + (size_t)nbase * TSTEPS;
#pragma unroll 1
    for (int i = lane; i < 32 * TSTEPS; i += 64) {
        const int cc = i / TSTEPS;
        ob[i] = dl[i + cc];
    }
}

extern "C" void kernel_launch(void* const* d_in, const int* in_sizes, int n_in,
                              void* d_out, int out_size, void* d_ws, size_t ws_size,
                              hipStream_t stream) {
    const float* feat = (const float*)d_in[0];
    const float* W1   = (const float*)d_in[1];
    const float* b1   = (const float*)d_in[2];
    const float* W2   = (const float*)d_in[3];
    const float* b2   = (const float*)d_in[4];
    const float* W3   = (const float*)d_in[5];
    const float* b3   = (const float*)d_in[6];
    float* out = (float*)d_out;

    const int N = in_sizes[0] / (TSTEPS * 3);
    const int block = 256;                  // 4 waves x 32 samples = 128 samples/block
    const int grid = (N + 127) / 128;
    ffn_mfma32<<<grid, block, 0, stream>>>(feat, W1, b1, W2, b2, W3, b3, out, N);
}